// Round 13
// baseline (197.061 us; speedup 1.0000x reference)
//
#include <hip/hip_runtime.h>
#include <hip/hip_bf16.h>
#include <stdint.h>

// Problem constants
#define B_   4
#define S_   2048
#define E_   1024
#define H_   16
#define D_   64
#define M_   (B_ * S_)     // 8192 rows
#define E3_  (3 * E_)      // 3072

#define QSCALE 0.18033688011112042f  // 0.125 * log2(e)

typedef __bf16 bf16_t;
typedef bf16_t bf16x8 __attribute__((ext_vector_type(8)));
typedef float  f32x4  __attribute__((ext_vector_type(4)));
typedef float  f32x16 __attribute__((ext_vector_type(16)));

__device__ __forceinline__ ushort f2bf(float f) {
  union { float f; uint32_t u; } v; v.f = f;
  uint32_t r = v.u + 0x7fffu + ((v.u >> 16) & 1u);
  return (ushort)(r >> 16);
}

__device__ __forceinline__ float bf2f(ushort u) {
  union { uint32_t u; float f; } v; v.u = ((uint32_t)u) << 16;
  return v.f;
}

__device__ __forceinline__ unsigned cvtpk(float lo, float hi_) {
  unsigned d;
  asm("v_cvt_pk_bf16_f32 %0, %1, %2" : "=v"(d) : "v"(lo), "v"(hi_));
  return d;
}

__device__ __forceinline__ void gload_lds16(const void* g, void* l) {
  __builtin_amdgcn_global_load_lds((const __attribute__((address_space(1))) void*)g,
                                   (__attribute__((address_space(3))) void*)l,
                                   16, 0, 0);
}

// ---------------------------------------------------------------- fused cvt f32->bf16 (3 regions, 1 launch)
__global__ __launch_bounds__(256) void cvt_all(const float* __restrict__ x,
                                               const float* __restrict__ w_in,
                                               const float* __restrict__ w_out,
                                               ushort* __restrict__ xb,
                                               ushort* __restrict__ winb,
                                               ushort* __restrict__ woutb) {
  const int stride = gridDim.x * blockDim.x;
  for (int i = blockIdx.x * blockDim.x + threadIdx.x; i < 3145728; i += stride) {
    const float* src; ushort* dst; int j; float sc = 1.f;
    if (i < 2097152)      { src = x;     dst = xb;    j = i; }
    else if (i < 2883584) { src = w_in;  dst = winb;  j = i - 2097152; if (j < 262144) sc = QSCALE; }
    else                  { src = w_out; dst = woutb; j = i - 2883584; }
    float4 v = reinterpret_cast<const float4*>(src)[j];
    ushort4 o;
    o.x = f2bf(v.x * sc); o.y = f2bf(v.y * sc); o.z = f2bf(v.z * sc); o.w = f2bf(v.w * sc);
    reinterpret_cast<ushort4*>(dst)[j] = o;
  }
}

// ---------------------------------------------------------------- GEMM 128x128, BK=32, ring-3, counted vmcnt
// MODE 0: bf16 out [Mdim][1024]. MODE 1: qkv split (cols<2048 -> qk bf16;
// cols>=2048 -> vT[(b*1024+col-2048)][2048] s-contiguous; q-bias scaled).
template <int MODE>
__global__ __launch_bounds__(256) void gemm_bt2(const ushort* __restrict__ A,
                                                const ushort* __restrict__ Bt,
                                                const float* __restrict__ bias,
                                                void* __restrict__ out0,
                                                ushort* __restrict__ vTout,
                                                int Ndim, int K) {
  __shared__ __align__(16) char lds[3][16384];  // [A 8KB | B 8KB]

  const int tid  = threadIdx.x;
  const int lane = tid & 63, wid = tid >> 6;
  const int w = wid;
  const int wr = wid >> 1, wc = wid & 1;

  const int nx  = Ndim >> 7;
  const int nwg = gridDim.x;
  const int b0  = blockIdx.x;
  const int nb  = (b0 & 7) * (nwg >> 3) + (b0 >> 3);
  const int bm  = (nb / nx) * 128, bn = (nb % nx) * 128;

  const int srow  = tid >> 2;
  const int sslot = (tid & 3) ^ (srow & 3) ^ ((srow >> 2) & 3);
  const ushort* aS = A  + (size_t)(bm + srow) * K + sslot * 8;
  const ushort* bS = Bt + (size_t)(bn + srow) * K + sslot * 8;

#define STAGE_A(T, BUF)                                                          \
  do {                                                                           \
    gload_lds16(aS + (size_t)(T) * 32,              (void*)((BUF) + w * 1024));  \
    gload_lds16(aS + (size_t)(T) * 32 + 64 * K,     (void*)((BUF) + 4096 + w * 1024)); \
  } while (0)
#define STAGE_B(T, BUF)                                                          \
  do {                                                                           \
    gload_lds16(bS + (size_t)(T) * 32,              (void*)((BUF) + 8192 + w * 1024)); \
    gload_lds16(bS + (size_t)(T) * 32 + 64 * K,     (void*)((BUF) + 12288 + w * 1024)); \
  } while (0)

  const int lr15 = lane & 15;
  const int ksub = lane >> 4;
  const int slot = (ksub ^ (lr15 & 3) ^ ((lr15 >> 2) & 3)) * 16;
  const int arow_b = (wr * 64 + lr15) * 64;
  const int brow_b = 8192 + (wc * 64 + lr15) * 64;

#define LDA4(BUF)                                                                \
  do {                                                                           \
    _Pragma("unroll")                                                            \
    for (int rb = 0; rb < 4; ++rb)                                               \
      af[rb] = *(const bf16x8*)((BUF) + arow_b + rb * 1024 + slot);              \
  } while (0)
#define LDB2(BUF, CB)                                                            \
  do {                                                                           \
    _Pragma("unroll")                                                            \
    for (int n = 0; n < 2; ++n)                                                  \
      bfr[n] = *(const bf16x8*)((BUF) + brow_b + ((CB) + n) * 1024 + slot);      \
  } while (0)
#define MFMA8(CB)                                                                \
  do {                                                                           \
    __builtin_amdgcn_s_setprio(1);                                               \
    _Pragma("unroll")                                                            \
    for (int rb = 0; rb < 4; ++rb)                                               \
      _Pragma("unroll")                                                          \
      for (int n = 0; n < 2; ++n)                                                \
        acc[rb][(CB) + n] = __builtin_amdgcn_mfma_f32_16x16x32_bf16(             \
            af[rb], bfr[n], acc[rb][(CB) + n], 0, 0, 0);                         \
    __builtin_amdgcn_s_setprio(0);                                               \
  } while (0)

  f32x4 acc[4][4] = {};
  bf16x8 af[4], bfr[2];

  char* buf0 = &lds[0][0];
  char* buf1 = &lds[1][0];
  char* buf2 = &lds[2][0];

  const int nt = K >> 5;

  STAGE_A(0, buf0); STAGE_B(0, buf0);
  STAGE_A(1, buf1); STAGE_B(1, buf1);
  asm volatile("s_waitcnt vmcnt(4)" ::: "memory");
  __builtin_amdgcn_s_barrier();
  __builtin_amdgcn_sched_barrier(0);

  for (int t = 0; t < nt; ++t) {
    if (t < nt - 2) STAGE_A(t + 2, buf2);
    LDA4(buf0);
    LDB2(buf0, 0);
    __builtin_amdgcn_s_barrier();
    asm volatile("s_waitcnt lgkmcnt(0)" ::: "memory");
    __builtin_amdgcn_sched_barrier(0);
    MFMA8(0);
    __builtin_amdgcn_s_barrier();
    __builtin_amdgcn_sched_barrier(0);
    if (t < nt - 2) STAGE_B(t + 2, buf2);
    LDB2(buf0, 2);
    __builtin_amdgcn_s_barrier();
    asm volatile("s_waitcnt lgkmcnt(0)" ::: "memory");
    __builtin_amdgcn_sched_barrier(0);
    MFMA8(2);
    if (t < nt - 2) asm volatile("s_waitcnt vmcnt(4)" ::: "memory");
    else if (t == nt - 2) asm volatile("s_waitcnt vmcnt(0)" ::: "memory");
    __builtin_amdgcn_s_barrier();
    __builtin_amdgcn_sched_barrier(0);
    char* tmp = buf0; buf0 = buf1; buf1 = buf2; buf2 = tmp;
  }

#pragma unroll
  for (int rb = 0; rb < 4; ++rb) {
#pragma unroll
    for (int cb = 0; cb < 4; ++cb) {
      const int col = bn + wc * 64 + cb * 16 + lr15;
      float bv = bias[col];
      if (MODE == 1 && col < 1024) bv *= QSCALE;
      const int row0 = bm + wr * 64 + rb * 16 + ksub * 4;
      if (MODE == 0) {
#pragma unroll
        for (int r = 0; r < 4; ++r)
          ((ushort*)out0)[(size_t)(row0 + r) * Ndim + col] = f2bf(acc[rb][cb][r] + bv);
      } else {
        if (col < 2048) {
#pragma unroll
          for (int r = 0; r < 4; ++r)
            ((ushort*)out0)[(size_t)(row0 + r) * 2048 + col] = f2bf(acc[rb][cb][r] + bv);
        } else {
          ushort4 vv;
          vv.x = f2bf(acc[rb][cb][0] + bv);
          vv.y = f2bf(acc[rb][cb][1] + bv);
          vv.z = f2bf(acc[rb][cb][2] + bv);
          vv.w = f2bf(acc[rb][cb][3] + bv);
          const size_t vidx = ((size_t)((row0 >> 11) * 1024 + (col - 2048))) * 2048 + (row0 & 2047);
          *reinterpret_cast<ushort4*>(&vTout[vidx]) = vv;
        }
      }
    }
  }
#undef STAGE_A
#undef STAGE_B
#undef LDA4
#undef LDB2
#undef MFMA8
}

// ---------------------------------------------------------------- causal flash attention, 2-way kv-split
// 1024 blocks = 64 bh x 8 qb x 2 halves; half h processes kv-tiles t ≡ h (mod 2) -> balanced.
// 8 waves x 32 q-rows; swapped QK^T (lane owns q = lane&31). Writes UN-normalized partial O (bf16)
// + per-q (m, l) to Op/ml; attn_merge combines the two halves.
__global__ __launch_bounds__(512) void attn_causal(const ushort* __restrict__ qk,
                                                   const ushort* __restrict__ vT,
                                                   ushort* __restrict__ Op,
                                                   float2* __restrict__ ml) {
  __shared__ __align__(16) char lds[2][16384];  // [buf][ K 8KB | Vt 8KB ]

  const int tid = threadIdx.x;
  const int w = tid >> 6, lane = tid & 63;
  const int l31 = lane & 31, hi = lane >> 5;

  const int bid = blockIdx.x;
  const int bh   = (bid & 7) * 8 + ((bid >> 3) & 7);  // 8 heads per XCD round
  const int half = (bid >> 6) & 1;
  const int qb   = 7 - (bid >> 7);                    // heavy q-blocks first
  const int b = bh >> 4, h = bh & 15;
  const int qw = qb * 256 + w * 32;
  const int q_g = qw + l31;
  const int my_tmax = (qw + 31) >> 6;
  const int niter = 2 * qb + 2;                       // tiles half, half+2, ..., 4qb+2+half

  // Q fragments (scale pre-folded into W_in q-rows)
  const ushort* qrow = qk + (size_t)(b * S_ + q_g) * 2048 + h * 64;
  bf16x8 qf[4];
#pragma unroll
  for (int st = 0; st < 4; ++st)
    qf[st] = *reinterpret_cast<const bf16x8*>(qrow + st * 16 + hi * 8);

  // staging: 512 threads x 16B = one 8KB tile each for K and Vt
  const int srow = tid >> 3;
  const int swz  = ((tid & 7) * 16) ^ ((srow & 7) << 4);
  const char* kbase = (const char*)qk + ((size_t)(b * S_ + srow) * 2048 + 1024 + h * 64) * 2 + swz;
  const char* vbase = (const char*)vT + ((size_t)(bh * 64 + srow) * 2048) * 2 + swz;

  f32x16 Ot0 = {}, Ot1 = {};
  float m_r = -__builtin_inff(), l_r = 0.f;

  const int kswz = ((l31 & 7) << 4);

#define STAGE(T, BUFI)                                                              \
  do {                                                                              \
    gload_lds16(kbase + (size_t)(T) * 262144, &lds[BUFI][w * 1024]);                \
    gload_lds16(vbase + (size_t)(T) * 128,    &lds[BUFI][8192 + w * 1024]);         \
  } while (0)

  STAGE(half, 0);
  for (int u = 0; u < niter; ++u) {
    const int t = half + 2 * u;
    const int bufi = u & 1;
    if (u < niter - 1) {
      STAGE(t + 2, bufi ^ 1);
      asm volatile("s_waitcnt vmcnt(2)" ::: "memory");
    } else {
      asm volatile("s_waitcnt vmcnt(0)" ::: "memory");
    }
    __builtin_amdgcn_s_barrier();
    __builtin_amdgcn_sched_barrier(0);

    if (t <= my_tmax) {
      const char* Kt = &lds[bufi][0];
      const char* Vp = &lds[bufi][8192];

      // ---- S^T = K @ Q^T : lane owns column q = l31 ----
      f32x16 T0 = {}, T1 = {};
#pragma unroll
      for (int st = 0; st < 4; ++st) {
        const int cb = (st * 32 + hi * 16) ^ kswz;
        bf16x8 k0 = *(const bf16x8*)(Kt + l31 * 128 + cb);
        bf16x8 k1 = *(const bf16x8*)(Kt + (32 + l31) * 128 + cb);
        T0 = __builtin_amdgcn_mfma_f32_32x32x16_bf16(k0, qf[st], T0, 0, 0, 0);
        T1 = __builtin_amdgcn_mfma_f32_32x32x16_bf16(k1, qf[st], T1, 0, 0, 0);
      }

      // ---- mask + online softmax (lane-local; defer-max THR=8; max3 chain) ----
      float p[32];
      const bool needmask = (t * 64 + 63) > qw;
      const int kvb = t * 64 + 4 * hi;
#pragma unroll
      for (int g = 0; g < 4; ++g) {
#pragma unroll
        for (int j = 0; j < 4; ++j) {
          float v0 = T0[4 * g + j], v1 = T1[4 * g + j];
          if (needmask) {
            const int kv0 = kvb + 8 * g + j;
            v0 = (kv0      <= q_g) ? v0 : -__builtin_inff();
            v1 = (kv0 + 32 <= q_g) ? v1 : -__builtin_inff();
          }
          p[4 * g + j] = v0;
          p[16 + 4 * g + j] = v1;
        }
      }
      float pmax = p[0];
#pragma unroll
      for (int i = 1; i < 31; i += 2) pmax = fmaxf(fmaxf(pmax, p[i]), p[i + 1]);
      pmax = fmaxf(pmax, p[31]);
      pmax = fmaxf(pmax, __shfl_xor(pmax, 32));

      if (!__all(pmax - m_r <= 8.f)) {
        const float mn = fmaxf(m_r, pmax);
        const float sc = exp2f(m_r - mn);
        m_r = mn;
        l_r *= sc;
#pragma unroll
        for (int i = 0; i < 16; ++i) { Ot0[i] *= sc; Ot1[i] *= sc; }
      }
      float sum = 0.f;
#pragma unroll
      for (int i = 0; i < 32; ++i) { p[i] = exp2f(p[i] - m_r); sum += p[i]; }
      sum += __shfl_xor(sum, 32);
      l_r += sum;

      // ---- P -> bf16 B-fragments via shfl_xor(32); PV swapped: O^T col = q ----
#pragma unroll
      for (int ks = 0; ks < 4; ++ks) {
        const unsigned a = cvtpk(p[8 * ks + 0], p[8 * ks + 1]);
        const unsigned bq = cvtpk(p[8 * ks + 2], p[8 * ks + 3]);
        const unsigned c = cvtpk(p[8 * ks + 4], p[8 * ks + 5]);
        const unsigned d = cvtpk(p[8 * ks + 6], p[8 * ks + 7]);
        const unsigned x = hi ? a : c;
        const unsigned y = hi ? bq : d;
        const unsigned xp = (unsigned)__shfl_xor((int)x, 32);
        const unsigned yp = (unsigned)__shfl_xor((int)y, 32);
        union { unsigned u[4]; bf16x8 v; } pa;
        pa.u[0] = hi ? xp : a;
        pa.u[1] = hi ? yp : bq;
        pa.u[2] = hi ? c : xp;
        pa.u[3] = hi ? d : yp;
        const int cb = (ks * 32 + hi * 16) ^ kswz;
        bf16x8 v0 = *(const bf16x8*)(Vp + l31 * 128 + cb);
        bf16x8 v1 = *(const bf16x8*)(Vp + (32 + l31) * 128 + cb);
        Ot0 = __builtin_amdgcn_mfma_f32_32x32x16_bf16(v0, pa.v, Ot0, 0, 0, 0);
        Ot1 = __builtin_amdgcn_mfma_f32_32x32x16_bf16(v1, pa.v, Ot1, 0, 0, 0);
      }
    }
    __builtin_amdgcn_s_barrier();
    __builtin_amdgcn_sched_barrier(0);
  }

  // ---- partial epilogue: raw O (no 1/l), plus (m,l) per q ----
  ushort* orow = Op + ((size_t)(half * 64 + bh) * 2048 + q_g) * 64;
#pragma unroll
  for (int g = 0; g < 4; ++g) {
#pragma unroll
    for (int jp = 0; jp < 2; ++jp) {
      const int d0 = 2 * jp + 8 * g + 4 * hi;
      const int r = 4 * g + 2 * jp;
      *(unsigned*)(orow + d0)      = cvtpk(Ot0[r], Ot0[r + 1]);
      *(unsigned*)(orow + 32 + d0) = cvtpk(Ot1[r], Ot1[r + 1]);
    }
  }
  if (hi == 0) {
    float2 v; v.x = m_r; v.y = l_r;
    ml[(size_t)(half * 64 + bh) * 2048 + q_g] = v;
  }
#undef STAGE
}

// ---------------------------------------------------------------- merge the two kv-halves
// Op: [2][64][2048][64] bf16 raw partial O. ml: [2][64][2048] (m,l).
// ctx[q][h*64+d] = (a0*O0 + a1*O1) / (a0*l0 + a1*l1), a_i = exp2(m_i - max).
__global__ __launch_bounds__(256) void attn_merge(const ushort* __restrict__ Op,
                                                  const float2* __restrict__ ml,
                                                  ushort* __restrict__ ctx) {
  const int gid = blockIdx.x * 256 + threadIdx.x;   // 1,048,576 threads
  const int r = gid >> 3;                           // bh*2048 + q
  const int c8 = (gid & 7) * 8;
  const int bh = r >> 11, q = r & 2047;
  const float2 m0 = ml[r];
  const float2 m1 = ml[131072 + r];
  const float M = fmaxf(m0.x, m1.x);
  const float a0 = exp2f(m0.x - M), a1 = exp2f(m1.x - M);
  const float inv = 1.0f / (a0 * m0.y + a1 * m1.y);
  const float s0 = a0 * inv, s1 = a1 * inv;

  const size_t base = (size_t)r * 64 + c8;
  ushort4 p0a = *(const ushort4*)(Op + base);
  ushort4 p0b = *(const ushort4*)(Op + base + 4);
  ushort4 p1a = *(const ushort4*)(Op + 8388608 + base);
  ushort4 p1b = *(const ushort4*)(Op + 8388608 + base + 4);

  float v[8];
  v[0] = s0 * bf2f(p0a.x) + s1 * bf2f(p1a.x);
  v[1] = s0 * bf2f(p0a.y) + s1 * bf2f(p1a.y);
  v[2] = s0 * bf2f(p0a.z) + s1 * bf2f(p1a.z);
  v[3] = s0 * bf2f(p0a.w) + s1 * bf2f(p1a.w);
  v[4] = s0 * bf2f(p0b.x) + s1 * bf2f(p1b.x);
  v[5] = s0 * bf2f(p0b.y) + s1 * bf2f(p1b.y);
  v[6] = s0 * bf2f(p0b.z) + s1 * bf2f(p1b.z);
  v[7] = s0 * bf2f(p0b.w) + s1 * bf2f(p1b.w);

  uint4 o;
  o.x = cvtpk(v[0], v[1]);
  o.y = cvtpk(v[2], v[3]);
  o.z = cvtpk(v[4], v[5]);
  o.w = cvtpk(v[6], v[7]);
  const size_t caddr = ((size_t)((bh >> 4) * 2048 + q)) * 1024 + (bh & 15) * 64 + c8;
  *reinterpret_cast<uint4*>(ctx + caddr) = o;
}

// ---------------------------------------------------------------- residual + LayerNorm (ao in bf16)
__global__ __launch_bounds__(256) void resid_ln(const float* __restrict__ x,
                                                const ushort* __restrict__ ao,
                                                const float* __restrict__ gamma,
                                                const float* __restrict__ beta,
                                                float* __restrict__ out) {
  const int row = blockIdx.x;
  const int tid = threadIdx.x;
  const size_t base = (size_t)row * E_;

  float4 xv = reinterpret_cast<const float4*>(x + base)[tid];
  ushort4 au = reinterpret_cast<const ushort4*>(ao + base)[tid];
  const float v0 = xv.x + bf2f(au.x), v1 = xv.y + bf2f(au.y);
  const float v2 = xv.z + bf2f(au.z), v3 = xv.w + bf2f(au.w);
  float s  = v0 + v1 + v2 + v3;
  float s2 = v0 * v0 + v1 * v1 + v2 * v2 + v3 * v3;
#pragma unroll
  for (int off = 32; off >= 1; off >>= 1) {
    s  += __shfl_xor(s, off);
    s2 += __shfl_xor(s2, off);
  }
  __shared__ float red[8];
  const int wid = tid >> 6, lane = tid & 63;
  if (lane == 0) { red[wid] = s; red[4 + wid] = s2; }
  __syncthreads();
  s  = red[0] + red[1] + red[2] + red[3];
  s2 = red[4] + red[5] + red[6] + red[7];
  const float mu  = s * (1.f / E_);
  const float var = s2 * (1.f / E_) - mu * mu;
  const float rsd = rsqrtf(var + 1e-5f);

  float4 gv = reinterpret_cast<const float4*>(gamma)[tid];
  float4 bv = reinterpret_cast<const float4*>(beta)[tid];
  float4 ov;
  ov.x = (v0 - mu) * rsd * gv.x + bv.x;
  ov.y = (v1 - mu) * rsd * gv.y + bv.y;
  ov.z = (v2 - mu) * rsd * gv.z + bv.z;
  ov.w = (v3 - mu) * rsd * gv.w + bv.w;
  reinterpret_cast<float4*>(out + base)[tid] = ov;
}

// ---------------------------------------------------------------- launch
extern "C" void kernel_launch(void* const* d_in, const int* in_sizes, int n_in,
                              void* d_out, int out_size, void* d_ws, size_t ws_size,
                              hipStream_t stream) {
  (void)in_sizes; (void)n_in; (void)out_size; (void)ws_size;
  const float* x     = (const float*)d_in[0];
  const float* w_in  = (const float*)d_in[1];
  const float* b_in  = (const float*)d_in[2];
  const float* w_out = (const float*)d_in[3];
  const float* b_out = (const float*)d_in[4];
  const float* gamma = (const float*)d_in[5];
  const float* beta  = (const float*)d_in[6];
  float* out = (float*)d_out;

  char* ws = (char*)d_ws;
  ushort* xb    = (ushort*)(ws);                          // 16 MB
  ushort* winb  = (ushort*)(ws + 16777216);               // 6 MB
  ushort* woutb = (ushort*)(ws + 23068672);               // 2 MB
  ushort* qkb   = (ushort*)(ws + 25165824);               // 32 MB  [8192][2048]
  ushort* vTb   = (ushort*)(ws + 58720256);               // 16 MB  [4096][2048]
  ushort* ctxb  = (ushort*)(ws + 75497472);               // 16 MB
  ushort* Opb   = (ushort*)(ws + 92274688);               // 32 MB  [2][64][2048][64] partial O
  float2* mlb   = (float2*)(ws + 125829120);              // 2 MB   [2][64][2048] (m,l)
  ushort* aob   = (ushort*)(ws + 92274688);               // alias Op (consumed before gemm2)

  cvt_all<<<dim3(2048), 256, 0, stream>>>(x, w_in, w_out, xb, winb, woutb);

  gemm_bt2<1><<<dim3(1536), 256, 0, stream>>>(xb, winb, b_in, qkb, vTb, E3_, E_);
  attn_causal<<<dim3(1024), 512, 0, stream>>>(qkb, vTb, Opb, mlb);
  attn_merge<<<dim3(4096), 256, 0, stream>>>(Opb, mlb, ctxb);
  gemm_bt2<0><<<dim3(512), 256, 0, stream>>>(ctxb, woutb, b_out, aob, nullptr, E_, E_);
  resid_ln<<<dim3(M_), 256, 0, stream>>>(x, aob, gamma, beta, out);
}

// Round 14
// 191.731 us; speedup vs baseline: 1.0278x; 1.0278x over previous
//
#include <hip/hip_runtime.h>
#include <hip/hip_bf16.h>
#include <stdint.h>

// Problem constants
#define B_   4
#define S_   2048
#define E_   1024
#define H_   16
#define D_   64
#define M_   (B_ * S_)     // 8192 rows
#define E3_  (3 * E_)      // 3072

#define QSCALE 0.18033688011112042f  // 0.125 * log2(e)

typedef __bf16 bf16_t;
typedef bf16_t bf16x8 __attribute__((ext_vector_type(8)));
typedef float  f32x4  __attribute__((ext_vector_type(4)));
typedef float  f32x16 __attribute__((ext_vector_type(16)));

__device__ __forceinline__ ushort f2bf(float f) {
  union { float f; uint32_t u; } v; v.f = f;
  uint32_t r = v.u + 0x7fffu + ((v.u >> 16) & 1u);
  return (ushort)(r >> 16);
}

__device__ __forceinline__ float bf2f(ushort u) {
  union { uint32_t u; float f; } v; v.u = ((uint32_t)u) << 16;
  return v.f;
}

__device__ __forceinline__ unsigned cvtpk(float lo, float hi_) {
  unsigned d;
  asm("v_cvt_pk_bf16_f32 %0, %1, %2" : "=v"(d) : "v"(lo), "v"(hi_));
  return d;
}

__device__ __forceinline__ void gload_lds16(const void* g, void* l) {
  __builtin_amdgcn_global_load_lds((const __attribute__((address_space(1))) void*)g,
                                   (__attribute__((address_space(3))) void*)l,
                                   16, 0, 0);
}

// ---------------------------------------------------------------- fused cvt f32->bf16 (3 regions, 1 launch)
__global__ __launch_bounds__(256) void cvt_all(const float* __restrict__ x,
                                               const float* __restrict__ w_in,
                                               const float* __restrict__ w_out,
                                               ushort* __restrict__ xb,
                                               ushort* __restrict__ winb,
                                               ushort* __restrict__ woutb) {
  const int stride = gridDim.x * blockDim.x;
  for (int i = blockIdx.x * blockDim.x + threadIdx.x; i < 3145728; i += stride) {
    const float* src; ushort* dst; int j; float sc = 1.f;
    if (i < 2097152)      { src = x;     dst = xb;    j = i; }
    else if (i < 2883584) { src = w_in;  dst = winb;  j = i - 2097152; if (j < 262144) sc = QSCALE; }
    else                  { src = w_out; dst = woutb; j = i - 2883584; }
    float4 v = reinterpret_cast<const float4*>(src)[j];
    ushort4 o;
    o.x = f2bf(v.x * sc); o.y = f2bf(v.y * sc); o.z = f2bf(v.z * sc); o.w = f2bf(v.w * sc);
    reinterpret_cast<ushort4*>(dst)[j] = o;
  }
}

// ---------------------------------------------------------------- GEMM 128x128, BK=32, ring-3, counted vmcnt
// Single phase per K-tile: {stage(t+2) || read 8 frags; lgkm0; 16 MFMA; vmcnt(4); 1 barrier}.
// MODE 0: bf16 out [Mdim][1024]. MODE 1: qkv split (cols<2048 -> qk bf16;
// cols>=2048 -> vT[(b*1024+col-2048)][2048] s-contiguous; q-bias scaled).
template <int MODE>
__global__ __launch_bounds__(256) void gemm_bt2(const ushort* __restrict__ A,
                                                const ushort* __restrict__ Bt,
                                                const float* __restrict__ bias,
                                                void* __restrict__ out0,
                                                ushort* __restrict__ vTout,
                                                int Ndim, int K) {
  __shared__ __align__(16) char lds[3][16384];  // [A 8KB | B 8KB]

  const int tid  = threadIdx.x;
  const int lane = tid & 63, wid = tid >> 6;
  const int w = wid;
  const int wr = wid >> 1, wc = wid & 1;

  const int nx  = Ndim >> 7;
  const int nwg = gridDim.x;
  const int b0  = blockIdx.x;
  const int nb  = (b0 & 7) * (nwg >> 3) + (b0 >> 3);
  const int bm  = (nb / nx) * 128, bn = (nb % nx) * 128;

  const int srow  = tid >> 2;
  const int sslot = (tid & 3) ^ (srow & 3) ^ ((srow >> 2) & 3);
  const ushort* aS = A  + (size_t)(bm + srow) * K + sslot * 8;
  const ushort* bS = Bt + (size_t)(bn + srow) * K + sslot * 8;

#define STAGE_A(T, BUF)                                                          \
  do {                                                                           \
    gload_lds16(aS + (size_t)(T) * 32,              (void*)((BUF) + w * 1024));  \
    gload_lds16(aS + (size_t)(T) * 32 + 64 * K,     (void*)((BUF) + 4096 + w * 1024)); \
  } while (0)
#define STAGE_B(T, BUF)                                                          \
  do {                                                                           \
    gload_lds16(bS + (size_t)(T) * 32,              (void*)((BUF) + 8192 + w * 1024)); \
    gload_lds16(bS + (size_t)(T) * 32 + 64 * K,     (void*)((BUF) + 12288 + w * 1024)); \
  } while (0)

  const int lr15 = lane & 15;
  const int ksub = lane >> 4;
  const int slot = (ksub ^ (lr15 & 3) ^ ((lr15 >> 2) & 3)) * 16;
  const int arow_b = (wr * 64 + lr15) * 64;
  const int brow_b = 8192 + (wc * 64 + lr15) * 64;

#define LDA4(BUF)                                                                \
  do {                                                                           \
    _Pragma("unroll")                                                            \
    for (int rb = 0; rb < 4; ++rb)                                               \
      af[rb] = *(const bf16x8*)((BUF) + arow_b + rb * 1024 + slot);              \
  } while (0)
#define LDB4(BUF)                                                                \
  do {                                                                           \
    _Pragma("unroll")                                                            \
    for (int n = 0; n < 4; ++n)                                                  \
      bfr[n] = *(const bf16x8*)((BUF) + brow_b + n * 1024 + slot);               \
  } while (0)
#define MFMA16()                                                                 \
  do {                                                                           \
    __builtin_amdgcn_s_setprio(1);                                               \
    _Pragma("unroll")                                                            \
    for (int rb = 0; rb < 4; ++rb)                                               \
      _Pragma("unroll")                                                          \
      for (int n = 0; n < 4; ++n)                                                \
        acc[rb][n] = __builtin_amdgcn_mfma_f32_16x16x32_bf16(                    \
            af[rb], bfr[n], acc[rb][n], 0, 0, 0);                                \
    __builtin_amdgcn_s_setprio(0);                                               \
  } while (0)

  f32x4 acc[4][4] = {};
  bf16x8 af[4], bfr[4];

  char* buf0 = &lds[0][0];
  char* buf1 = &lds[1][0];
  char* buf2 = &lds[2][0];

  const int nt = K >> 5;

  STAGE_A(0, buf0); STAGE_B(0, buf0);
  STAGE_A(1, buf1); STAGE_B(1, buf1);
  asm volatile("s_waitcnt vmcnt(4)" ::: "memory");
  __builtin_amdgcn_s_barrier();
  __builtin_amdgcn_sched_barrier(0);

  for (int t = 0; t < nt; ++t) {
    if (t < nt - 2) { STAGE_A(t + 2, buf2); STAGE_B(t + 2, buf2); }
    LDA4(buf0);
    LDB4(buf0);
    asm volatile("s_waitcnt lgkmcnt(0)" ::: "memory");
    __builtin_amdgcn_sched_barrier(0);
    MFMA16();
    if (t < nt - 2) asm volatile("s_waitcnt vmcnt(4)" ::: "memory");
    else if (t == nt - 2) asm volatile("s_waitcnt vmcnt(0)" ::: "memory");
    __builtin_amdgcn_s_barrier();
    __builtin_amdgcn_sched_barrier(0);
    char* tmp = buf0; buf0 = buf1; buf1 = buf2; buf2 = tmp;
  }

  // ---- epilogue ----
#pragma unroll
  for (int rb = 0; rb < 4; ++rb) {
#pragma unroll
    for (int cb = 0; cb < 4; ++cb) {
      const int col = bn + wc * 64 + cb * 16 + lr15;
      float bv = bias[col];
      if (MODE == 1 && col < 1024) bv *= QSCALE;
      const int row0 = bm + wr * 64 + rb * 16 + ksub * 4;
      if (MODE == 0) {
#pragma unroll
        for (int r = 0; r < 4; ++r)
          ((ushort*)out0)[(size_t)(row0 + r) * Ndim + col] = f2bf(acc[rb][cb][r] + bv);
      } else {
        if (col < 2048) {
#pragma unroll
          for (int r = 0; r < 4; ++r)
            ((ushort*)out0)[(size_t)(row0 + r) * 2048 + col] = f2bf(acc[rb][cb][r] + bv);
        } else {
          ushort4 vv;
          vv.x = f2bf(acc[rb][cb][0] + bv);
          vv.y = f2bf(acc[rb][cb][1] + bv);
          vv.z = f2bf(acc[rb][cb][2] + bv);
          vv.w = f2bf(acc[rb][cb][3] + bv);
          const size_t vidx = ((size_t)((row0 >> 11) * 1024 + (col - 2048))) * 2048 + (row0 & 2047);
          *reinterpret_cast<ushort4*>(&vTout[vidx]) = vv;
        }
      }
    }
  }
#undef STAGE_A
#undef STAGE_B
#undef LDA4
#undef LDB4
#undef MFMA16
}

// ---------------------------------------------------------------- causal flash attention, kv-PAIR loop (R12, 81.4us)
// 8 waves x 32 q-rows = 256 q/block; per iteration: stage next PAIR of 64-kv tiles
// (counted vmcnt(4)), compute both tiles between ONE barrier pair. LDS 2 x 32KB.
__global__ __launch_bounds__(512) void attn_causal(const ushort* __restrict__ qk,
                                                   const ushort* __restrict__ vT,
                                                   ushort* __restrict__ ctx) {
  __shared__ __align__(16) char lds[2][32768];  // [buf][K0 8K|K1 8K|V0 8K|V1 8K]

  const int tid = threadIdx.x;
  const int w = tid >> 6, lane = tid & 63;
  const int l31 = lane & 31, hi = lane >> 5;

  const int bid = blockIdx.x;
  const int bh = (bid & 7) * 8 + ((bid >> 3) & 7);  // 8 heads per XCD round
  const int g6 = bid >> 6;
  const int qb = (g6 < 4) ? (7 - g6) : (g6 - 4);    // pair (7,0),(6,1),(5,2),(4,3) per CU
  const int b = bh >> 4, h = bh & 15;
  const int qw = qb * 256 + w * 32;
  const int q_g = qw + l31;
  const int my_tmax = (qw + 31) >> 6;
  const int U = 2 * qb + 2;                         // kv-tile pairs

  // Q fragments (scale pre-folded into W_in q-rows)
  const ushort* qrow = qk + (size_t)(b * S_ + q_g) * 2048 + h * 64;
  bf16x8 qf[4];
#pragma unroll
  for (int st = 0; st < 4; ++st)
    qf[st] = *reinterpret_cast<const bf16x8*>(qrow + st * 16 + hi * 8);

  // staging: 512 threads x 16B = 8KB per gload round
  const int srow = tid >> 3;
  const int swz  = ((tid & 7) * 16) ^ ((srow & 7) << 4);
  const char* kbase = (const char*)qk + ((size_t)(b * S_ + srow) * 2048 + 1024 + h * 64) * 2 + swz;
  const char* vbase = (const char*)vT + ((size_t)(bh * 64 + srow) * 2048) * 2 + swz;

  f32x16 Ot0 = {}, Ot1 = {};
  float m_r = -__builtin_inff(), l_r = 0.f;

  const int kswz = ((l31 & 7) << 4);

#define STAGE_PAIR(U2, BUFI)                                                            \
  do {                                                                                  \
    const size_t t0_ = (size_t)(U2) * 2;                                                \
    gload_lds16(kbase + t0_ * 262144,          &lds[BUFI][w * 1024]);                   \
    gload_lds16(kbase + (t0_ + 1) * 262144,    &lds[BUFI][8192 + w * 1024]);            \
    gload_lds16(vbase + t0_ * 128,             &lds[BUFI][16384 + w * 1024]);           \
    gload_lds16(vbase + t0_ * 128 + 128,       &lds[BUFI][24576 + w * 1024]);           \
  } while (0)

  STAGE_PAIR(0, 0);
  for (int u = 0; u < U; ++u) {
    const int bufi = u & 1;
    if (u < U - 1) {
      STAGE_PAIR(u + 1, bufi ^ 1);
      asm volatile("s_waitcnt vmcnt(4)" ::: "memory");
    } else {
      asm volatile("s_waitcnt vmcnt(0)" ::: "memory");
    }
    __builtin_amdgcn_s_barrier();
    __builtin_amdgcn_sched_barrier(0);

#pragma unroll
    for (int s = 0; s < 2; ++s) {
      const int t = 2 * u + s;
      if (t <= my_tmax) {
        const char* Kt = &lds[bufi][s * 8192];
        const char* Vp = &lds[bufi][16384 + s * 8192];

        // ---- S^T = K @ Q^T : lane owns column q = l31 ----
        f32x16 T0 = {}, T1 = {};
#pragma unroll
        for (int st = 0; st < 4; ++st) {
          const int cb = (st * 32 + hi * 16) ^ kswz;
          bf16x8 k0 = *(const bf16x8*)(Kt + l31 * 128 + cb);
          bf16x8 k1 = *(const bf16x8*)(Kt + (32 + l31) * 128 + cb);
          T0 = __builtin_amdgcn_mfma_f32_32x32x16_bf16(k0, qf[st], T0, 0, 0, 0);
          T1 = __builtin_amdgcn_mfma_f32_32x32x16_bf16(k1, qf[st], T1, 0, 0, 0);
        }

        // ---- mask + online softmax (lane-local; defer-max THR=8; max3 chain) ----
        float p[32];
        const bool needmask = (t * 64 + 63) > qw;
        const int kvb = t * 64 + 4 * hi;
#pragma unroll
        for (int g = 0; g < 4; ++g) {
#pragma unroll
          for (int j = 0; j < 4; ++j) {
            float v0 = T0[4 * g + j], v1 = T1[4 * g + j];
            if (needmask) {
              const int kv0 = kvb + 8 * g + j;
              v0 = (kv0      <= q_g) ? v0 : -__builtin_inff();
              v1 = (kv0 + 32 <= q_g) ? v1 : -__builtin_inff();
            }
            p[4 * g + j] = v0;
            p[16 + 4 * g + j] = v1;
          }
        }
        float pmax = p[0];
#pragma unroll
        for (int i = 1; i < 31; i += 2) pmax = fmaxf(fmaxf(pmax, p[i]), p[i + 1]);
        pmax = fmaxf(pmax, p[31]);
        pmax = fmaxf(pmax, __shfl_xor(pmax, 32));

        if (!__all(pmax - m_r <= 8.f)) {
          const float mn = fmaxf(m_r, pmax);
          const float sc = exp2f(m_r - mn);
          m_r = mn;
          l_r *= sc;
#pragma unroll
          for (int i = 0; i < 16; ++i) { Ot0[i] *= sc; Ot1[i] *= sc; }
        }
        float sum = 0.f;
#pragma unroll
        for (int i = 0; i < 32; ++i) { p[i] = exp2f(p[i] - m_r); sum += p[i]; }
        sum += __shfl_xor(sum, 32);
        l_r += sum;

        // ---- P -> bf16 B-fragments via shfl_xor(32); PV swapped: O^T col = q ----
#pragma unroll
        for (int ks = 0; ks < 4; ++ks) {
          const unsigned a = cvtpk(p[8 * ks + 0], p[8 * ks + 1]);
          const unsigned bq = cvtpk(p[8 * ks + 2], p[8 * ks + 3]);
          const unsigned c = cvtpk(p[8 * ks + 4], p[8 * ks + 5]);
          const unsigned d = cvtpk(p[8 * ks + 6], p[8 * ks + 7]);
          const unsigned x = hi ? a : c;
          const unsigned y = hi ? bq : d;
          const unsigned xp = (unsigned)__shfl_xor((int)x, 32);
          const unsigned yp = (unsigned)__shfl_xor((int)y, 32);
          union { unsigned u[4]; bf16x8 v; } pa;
          pa.u[0] = hi ? xp : a;
          pa.u[1] = hi ? yp : bq;
          pa.u[2] = hi ? c : xp;
          pa.u[3] = hi ? d : yp;
          const int cb = (ks * 32 + hi * 16) ^ kswz;
          bf16x8 v0 = *(const bf16x8*)(Vp + l31 * 128 + cb);
          bf16x8 v1 = *(const bf16x8*)(Vp + (32 + l31) * 128 + cb);
          Ot0 = __builtin_amdgcn_mfma_f32_32x32x16_bf16(v0, pa.v, Ot0, 0, 0, 0);
          Ot1 = __builtin_amdgcn_mfma_f32_32x32x16_bf16(v1, pa.v, Ot1, 0, 0, 0);
        }
      }
    }
    __builtin_amdgcn_s_barrier();
    __builtin_amdgcn_sched_barrier(0);
  }

  // ---- epilogue: ctx[q][d] = O^T[d][q] / l ----
  const float inv = 1.0f / l_r;
  ushort* crow = ctx + (size_t)(b * S_ + q_g) * 1024 + h * 64;
#pragma unroll
  for (int g = 0; g < 4; ++g) {
#pragma unroll
    for (int jp = 0; jp < 2; ++jp) {
      const int d0 = 2 * jp + 8 * g + 4 * hi;
      const int r = 4 * g + 2 * jp;
      *(unsigned*)(crow + d0)      = cvtpk(Ot0[r] * inv, Ot0[r + 1] * inv);
      *(unsigned*)(crow + 32 + d0) = cvtpk(Ot1[r] * inv, Ot1[r + 1] * inv);
    }
  }
#undef STAGE_PAIR
}

// ---------------------------------------------------------------- residual + LayerNorm (ao in bf16)
__global__ __launch_bounds__(256) void resid_ln(const float* __restrict__ x,
                                                const ushort* __restrict__ ao,
                                                const float* __restrict__ gamma,
                                                const float* __restrict__ beta,
                                                float* __restrict__ out) {
  const int row = blockIdx.x;
  const int tid = threadIdx.x;
  const size_t base = (size_t)row * E_;

  float4 xv = reinterpret_cast<const float4*>(x + base)[tid];
  ushort4 au = reinterpret_cast<const ushort4*>(ao + base)[tid];
  const float v0 = xv.x + bf2f(au.x), v1 = xv.y + bf2f(au.y);
  const float v2 = xv.z + bf2f(au.z), v3 = xv.w + bf2f(au.w);
  float s  = v0 + v1 + v2 + v3;
  float s2 = v0 * v0 + v1 * v1 + v2 * v2 + v3 * v3;
#pragma unroll
  for (int off = 32; off >= 1; off >>= 1) {
    s  += __shfl_xor(s, off);
    s2 += __shfl_xor(s2, off);
  }
  __shared__ float red[8];
  const int wid = tid >> 6, lane = tid & 63;
  if (lane == 0) { red[wid] = s; red[4 + wid] = s2; }
  __syncthreads();
  s  = red[0] + red[1] + red[2] + red[3];
  s2 = red[4] + red[5] + red[6] + red[7];
  const float mu  = s * (1.f / E_);
  const float var = s2 * (1.f / E_) - mu * mu;
  const float rsd = rsqrtf(var + 1e-5f);

  float4 gv = reinterpret_cast<const float4*>(gamma)[tid];
  float4 bv = reinterpret_cast<const float4*>(beta)[tid];
  float4 ov;
  ov.x = (v0 - mu) * rsd * gv.x + bv.x;
  ov.y = (v1 - mu) * rsd * gv.y + bv.y;
  ov.z = (v2 - mu) * rsd * gv.z + bv.z;
  ov.w = (v3 - mu) * rsd * gv.w + bv.w;
  reinterpret_cast<float4*>(out + base)[tid] = ov;
}

// ---------------------------------------------------------------- launch
extern "C" void kernel_launch(void* const* d_in, const int* in_sizes, int n_in,
                              void* d_out, int out_size, void* d_ws, size_t ws_size,
                              hipStream_t stream) {
  (void)in_sizes; (void)n_in; (void)out_size; (void)ws_size;
  const float* x     = (const float*)d_in[0];
  const float* w_in  = (const float*)d_in[1];
  const float* b_in  = (const float*)d_in[2];
  const float* w_out = (const float*)d_in[3];
  const float* b_out = (const float*)d_in[4];
  const float* gamma = (const float*)d_in[5];
  const float* beta  = (const float*)d_in[6];
  float* out = (float*)d_out;

  char* ws = (char*)d_ws;
  ushort* xb    = (ushort*)(ws);                          // 16 MB
  ushort* winb  = (ushort*)(ws + 16777216);               // 6 MB
  ushort* woutb = (ushort*)(ws + 23068672);               // 2 MB
  ushort* qkb   = (ushort*)(ws + 25165824);               // 32 MB  [8192][2048]
  ushort* vTb   = (ushort*)(ws + 58720256);               // 16 MB  [4096][2048]
  ushort* ctxb  = (ushort*)(ws + 75497472);               // 16 MB
  ushort* aob   = (ushort*)(ws + 92274688);               // 16 MB  bf16 attn-out

  cvt_all<<<dim3(2048), 256, 0, stream>>>(x, w_in, w_out, xb, winb, woutb);

  gemm_bt2<1><<<dim3(1536), 256, 0, stream>>>(xb, winb, b_in, qkb, vTb, E3_, E_);
  attn_causal<<<dim3(512), 512, 0, stream>>>(qkb, vTb, ctxb);
  gemm_bt2<0><<<dim3(512), 256, 0, stream>>>(ctxb, woutb, b_out, aob, nullptr, E_, E_);
  resid_ln<<<dim3(M_), 256, 0, stream>>>(x, aob, gamma, beta, out);
}

// Round 17
// 191.711 us; speedup vs baseline: 1.0279x; 1.0001x over previous
//
#include <hip/hip_runtime.h>
#include <hip/hip_bf16.h>
#include <stdint.h>

// Problem constants
#define B_   4
#define S_   2048
#define E_   1024
#define H_   16
#define D_   64
#define M_   (B_ * S_)     // 8192 rows
#define E3_  (3 * E_)      // 3072

#define QSCALE 0.18033688011112042f  // 0.125 * log2(e)

typedef __bf16 bf16_t;
typedef bf16_t bf16x8 __attribute__((ext_vector_type(8)));
typedef float  f32x4  __attribute__((ext_vector_type(4)));
typedef float  f32x16 __attribute__((ext_vector_type(16)));

__device__ __forceinline__ ushort f2bf(float f) {
  union { float f; uint32_t u; } v; v.f = f;
  uint32_t r = v.u + 0x7fffu + ((v.u >> 16) & 1u);
  return (ushort)(r >> 16);
}

__device__ __forceinline__ float bf2f(ushort u) {
  union { uint32_t u; float f; } v; v.u = ((uint32_t)u) << 16;
  return v.f;
}

__device__ __forceinline__ unsigned cvtpk(float lo, float hi_) {
  unsigned d;
  asm("v_cvt_pk_bf16_f32 %0, %1, %2" : "=v"(d) : "v"(lo), "v"(hi_));
  return d;
}

__device__ __forceinline__ void gload_lds16(const void* g, void* l) {
  __builtin_amdgcn_global_load_lds((const __attribute__((address_space(1))) void*)g,
                                   (__attribute__((address_space(3))) void*)l,
                                   16, 0, 0);
}

// ---------------------------------------------------------------- fused cvt f32->bf16 (3 regions, 1 launch)
__global__ __launch_bounds__(256) void cvt_all(const float* __restrict__ x,
                                               const float* __restrict__ w_in,
                                               const float* __restrict__ w_out,
                                               ushort* __restrict__ xb,
                                               ushort* __restrict__ winb,
                                               ushort* __restrict__ woutb) {
  const int stride = gridDim.x * blockDim.x;
  for (int i = blockIdx.x * blockDim.x + threadIdx.x; i < 3145728; i += stride) {
    const float* src; ushort* dst; int j; float sc = 1.f;
    if (i < 2097152)      { src = x;     dst = xb;    j = i; }
    else if (i < 2883584) { src = w_in;  dst = winb;  j = i - 2097152; if (j < 262144) sc = QSCALE; }
    else                  { src = w_out; dst = woutb; j = i - 2883584; }
    float4 v = reinterpret_cast<const float4*>(src)[j];
    ushort4 o;
    o.x = f2bf(v.x * sc); o.y = f2bf(v.y * sc); o.z = f2bf(v.z * sc); o.w = f2bf(v.w * sc);
    reinterpret_cast<ushort4*>(dst)[j] = o;
  }
}

// ---------------------------------------------------------------- GEMM 128x128, BK=32, ring-3, counted vmcnt
// Single phase per K-tile: {stage(t+2) || read 8 frags; lgkm0; 16 MFMA; vmcnt(4); 1 barrier}.
// MODE 0: bf16 out [Mdim][1024]. MODE 1: qkv split (cols<2048 -> qk bf16;
// cols>=2048 -> vT[(b*1024+col-2048)][2048] s-contiguous; q-bias scaled).
template <int MODE>
__global__ __launch_bounds__(256) void gemm_bt2(const ushort* __restrict__ A,
                                                const ushort* __restrict__ Bt,
                                                const float* __restrict__ bias,
                                                void* __restrict__ out0,
                                                ushort* __restrict__ vTout,
                                                int Ndim, int K) {
  __shared__ __align__(16) char lds[3][16384];  // [A 8KB | B 8KB]

  const int tid  = threadIdx.x;
  const int lane = tid & 63, wid = tid >> 6;
  const int w = wid;
  const int wr = wid >> 1, wc = wid & 1;

  const int nx  = Ndim >> 7;
  const int nwg = gridDim.x;
  const int b0  = blockIdx.x;
  const int nb  = (b0 & 7) * (nwg >> 3) + (b0 >> 3);
  const int bm  = (nb / nx) * 128, bn = (nb % nx) * 128;

  const int srow  = tid >> 2;
  const int sslot = (tid & 3) ^ (srow & 3) ^ ((srow >> 2) & 3);
  const ushort* aS = A  + (size_t)(bm + srow) * K + sslot * 8;
  const ushort* bS = Bt + (size_t)(bn + srow) * K + sslot * 8;

#define STAGE_A(T, BUF)                                                          \
  do {                                                                           \
    gload_lds16(aS + (size_t)(T) * 32,              (void*)((BUF) + w * 1024));  \
    gload_lds16(aS + (size_t)(T) * 32 + 64 * K,     (void*)((BUF) + 4096 + w * 1024)); \
  } while (0)
#define STAGE_B(T, BUF)                                                          \
  do {                                                                           \
    gload_lds16(bS + (size_t)(T) * 32,              (void*)((BUF) + 8192 + w * 1024)); \
    gload_lds16(bS + (size_t)(T) * 32 + 64 * K,     (void*)((BUF) + 12288 + w * 1024)); \
  } while (0)

  const int lr15 = lane & 15;
  const int ksub = lane >> 4;
  const int slot = (ksub ^ (lr15 & 3) ^ ((lr15 >> 2) & 3)) * 16;
  const int arow_b = (wr * 64 + lr15) * 64;
  const int brow_b = 8192 + (wc * 64 + lr15) * 64;

#define LDA4(BUF)                                                                \
  do {                                                                           \
    _Pragma("unroll")                                                            \
    for (int rb = 0; rb < 4; ++rb)                                               \
      af[rb] = *(const bf16x8*)((BUF) + arow_b + rb * 1024 + slot);              \
  } while (0)
#define LDB4(BUF)                                                                \
  do {                                                                           \
    _Pragma("unroll")                                                            \
    for (int n = 0; n < 4; ++n)                                                  \
      bfr[n] = *(const bf16x8*)((BUF) + brow_b + n * 1024 + slot);               \
  } while (0)
#define MFMA16()                                                                 \
  do {                                                                           \
    __builtin_amdgcn_s_setprio(1);                                               \
    _Pragma("unroll")                                                            \
    for (int rb = 0; rb < 4; ++rb)                                               \
      _Pragma("unroll")                                                          \
      for (int n = 0; n < 4; ++n)                                                \
        acc[rb][n] = __builtin_amdgcn_mfma_f32_16x16x32_bf16(                    \
            af[rb], bfr[n], acc[rb][n], 0, 0, 0);                                \
    __builtin_amdgcn_s_setprio(0);                                               \
  } while (0)

  f32x4 acc[4][4] = {};
  bf16x8 af[4], bfr[4];

  char* buf0 = &lds[0][0];
  char* buf1 = &lds[1][0];
  char* buf2 = &lds[2][0];

  const int nt = K >> 5;

  STAGE_A(0, buf0); STAGE_B(0, buf0);
  STAGE_A(1, buf1); STAGE_B(1, buf1);
  asm volatile("s_waitcnt vmcnt(4)" ::: "memory");
  __builtin_amdgcn_s_barrier();
  __builtin_amdgcn_sched_barrier(0);

  for (int t = 0; t < nt; ++t) {
    if (t < nt - 2) { STAGE_A(t + 2, buf2); STAGE_B(t + 2, buf2); }
    LDA4(buf0);
    LDB4(buf0);
    asm volatile("s_waitcnt lgkmcnt(0)" ::: "memory");
    __builtin_amdgcn_sched_barrier(0);
    MFMA16();
    if (t < nt - 2) asm volatile("s_waitcnt vmcnt(4)" ::: "memory");
    else if (t == nt - 2) asm volatile("s_waitcnt vmcnt(0)" ::: "memory");
    __builtin_amdgcn_s_barrier();
    __builtin_amdgcn_sched_barrier(0);
    char* tmp = buf0; buf0 = buf1; buf1 = buf2; buf2 = tmp;
  }

  // ---- epilogue ----
#pragma unroll
  for (int rb = 0; rb < 4; ++rb) {
#pragma unroll
    for (int cb = 0; cb < 4; ++cb) {
      const int col = bn + wc * 64 + cb * 16 + lr15;
      float bv = bias[col];
      if (MODE == 1 && col < 1024) bv *= QSCALE;
      const int row0 = bm + wr * 64 + rb * 16 + ksub * 4;
      if (MODE == 0) {
#pragma unroll
        for (int r = 0; r < 4; ++r)
          ((ushort*)out0)[(size_t)(row0 + r) * Ndim + col] = f2bf(acc[rb][cb][r] + bv);
      } else {
        if (col < 2048) {
#pragma unroll
          for (int r = 0; r < 4; ++r)
            ((ushort*)out0)[(size_t)(row0 + r) * 2048 + col] = f2bf(acc[rb][cb][r] + bv);
        } else {
          ushort4 vv;
          vv.x = f2bf(acc[rb][cb][0] + bv);
          vv.y = f2bf(acc[rb][cb][1] + bv);
          vv.z = f2bf(acc[rb][cb][2] + bv);
          vv.w = f2bf(acc[rb][cb][3] + bv);
          const size_t vidx = ((size_t)((row0 >> 11) * 1024 + (col - 2048))) * 2048 + (row0 & 2047);
          *reinterpret_cast<ushort4*>(&vTout[vidx]) = vv;
        }
      }
    }
  }
#undef STAGE_A
#undef STAGE_B
#undef LDA4
#undef LDB4
#undef MFMA16
}

// ---------------------------------------------------------------- causal flash attention, kv-PAIR loop
// 8 waves x 32 q-rows = 256 q/block; per iteration: stage next PAIR of 64-kv tiles
// (counted vmcnt(4)), compute both tiles between ONE barrier pair. LDS 2 x 32KB.
// Cross-half ops via __shfl_xor(.,32) ONLY — permlane32_swap builtin falsified (R2/R16).
__global__ __launch_bounds__(512) void attn_causal(const ushort* __restrict__ qk,
                                                   const ushort* __restrict__ vT,
                                                   ushort* __restrict__ ctx) {
  __shared__ __align__(16) char lds[2][32768];  // [buf][K0 8K|K1 8K|V0 8K|V1 8K]

  const int tid = threadIdx.x;
  const int w = tid >> 6, lane = tid & 63;
  const int l31 = lane & 31, hi = lane >> 5;

  const int bid = blockIdx.x;
  const int bh = (bid & 7) * 8 + ((bid >> 3) & 7);  // 8 heads per XCD round
  const int g6 = bid >> 6;
  const int qb = (g6 < 4) ? (7 - g6) : (g6 - 4);    // pair (7,0),(6,1),(5,2),(4,3) per CU
  const int b = bh >> 4, h = bh & 15;
  const int qw = qb * 256 + w * 32;
  const int q_g = qw + l31;
  const int my_tmax = (qw + 31) >> 6;
  const int U = 2 * qb + 2;                         // kv-tile pairs

  // Q fragments (scale pre-folded into W_in q-rows)
  const ushort* qrow = qk + (size_t)(b * S_ + q_g) * 2048 + h * 64;
  bf16x8 qf[4];
#pragma unroll
  for (int st = 0; st < 4; ++st)
    qf[st] = *reinterpret_cast<const bf16x8*>(qrow + st * 16 + hi * 8);

  // staging: 512 threads x 16B = 8KB per gload round
  const int srow = tid >> 3;
  const int swz  = ((tid & 7) * 16) ^ ((srow & 7) << 4);
  const char* kbase = (const char*)qk + ((size_t)(b * S_ + srow) * 2048 + 1024 + h * 64) * 2 + swz;
  const char* vbase = (const char*)vT + ((size_t)(bh * 64 + srow) * 2048) * 2 + swz;

  f32x16 Ot0 = {}, Ot1 = {};
  float m_r = -__builtin_inff(), l_r = 0.f;

  const int kswz = ((l31 & 7) << 4);

#define STAGE_PAIR(U2, BUFI)                                                            \
  do {                                                                                  \
    const size_t t0_ = (size_t)(U2) * 2;                                                \
    gload_lds16(kbase + t0_ * 262144,          &lds[BUFI][w * 1024]);                   \
    gload_lds16(kbase + (t0_ + 1) * 262144,    &lds[BUFI][8192 + w * 1024]);            \
    gload_lds16(vbase + t0_ * 128,             &lds[BUFI][16384 + w * 1024]);           \
    gload_lds16(vbase + t0_ * 128 + 128,       &lds[BUFI][24576 + w * 1024]);           \
  } while (0)

  STAGE_PAIR(0, 0);
  for (int u = 0; u < U; ++u) {
    const int bufi = u & 1;
    if (u < U - 1) {
      STAGE_PAIR(u + 1, bufi ^ 1);
      asm volatile("s_waitcnt vmcnt(4)" ::: "memory");
    } else {
      asm volatile("s_waitcnt vmcnt(0)" ::: "memory");
    }
    __builtin_amdgcn_s_barrier();
    __builtin_amdgcn_sched_barrier(0);

#pragma unroll
    for (int s = 0; s < 2; ++s) {
      const int t = 2 * u + s;
      if (t <= my_tmax) {
        const char* Kt = &lds[bufi][s * 8192];
        const char* Vp = &lds[bufi][16384 + s * 8192];

        // ---- S^T = K @ Q^T : lane owns column q = l31 ----
        f32x16 T0 = {}, T1 = {};
#pragma unroll
        for (int st = 0; st < 4; ++st) {
          const int cb = (st * 32 + hi * 16) ^ kswz;
          bf16x8 k0 = *(const bf16x8*)(Kt + l31 * 128 + cb);
          bf16x8 k1 = *(const bf16x8*)(Kt + (32 + l31) * 128 + cb);
          T0 = __builtin_amdgcn_mfma_f32_32x32x16_bf16(k0, qf[st], T0, 0, 0, 0);
          T1 = __builtin_amdgcn_mfma_f32_32x32x16_bf16(k1, qf[st], T1, 0, 0, 0);
        }

        // ---- mask + online softmax (lane-local; defer-max THR=8; max3 chain) ----
        float p[32];
        const bool needmask = (t * 64 + 63) > qw;
        const int kvb = t * 64 + 4 * hi;
#pragma unroll
        for (int g = 0; g < 4; ++g) {
#pragma unroll
          for (int j = 0; j < 4; ++j) {
            float v0 = T0[4 * g + j], v1 = T1[4 * g + j];
            if (needmask) {
              const int kv0 = kvb + 8 * g + j;
              v0 = (kv0      <= q_g) ? v0 : -__builtin_inff();
              v1 = (kv0 + 32 <= q_g) ? v1 : -__builtin_inff();
            }
            p[4 * g + j] = v0;
            p[16 + 4 * g + j] = v1;
          }
        }
        float pmax = p[0];
#pragma unroll
        for (int i = 1; i < 31; i += 2) pmax = fmaxf(fmaxf(pmax, p[i]), p[i + 1]);
        pmax = fmaxf(pmax, p[31]);
        pmax = fmaxf(pmax, __shfl_xor(pmax, 32));

        if (!__all(pmax - m_r <= 8.f)) {
          const float mn = fmaxf(m_r, pmax);
          const float sc = exp2f(m_r - mn);
          m_r = mn;
          l_r *= sc;
#pragma unroll
          for (int i = 0; i < 16; ++i) { Ot0[i] *= sc; Ot1[i] *= sc; }
        }
        float sum = 0.f;
#pragma unroll
        for (int i = 0; i < 32; ++i) { p[i] = exp2f(p[i] - m_r); sum += p[i]; }
        sum += __shfl_xor(sum, 32);
        l_r += sum;

        // ---- P -> bf16 B-fragments via shfl_xor(32); PV swapped: O^T col = q ----
#pragma unroll
        for (int ks = 0; ks < 4; ++ks) {
          const unsigned a = cvtpk(p[8 * ks + 0], p[8 * ks + 1]);
          const unsigned bq = cvtpk(p[8 * ks + 2], p[8 * ks + 3]);
          const unsigned c = cvtpk(p[8 * ks + 4], p[8 * ks + 5]);
          const unsigned d = cvtpk(p[8 * ks + 6], p[8 * ks + 7]);
          const unsigned x = hi ? a : c;
          const unsigned y = hi ? bq : d;
          const unsigned xp = (unsigned)__shfl_xor((int)x, 32);
          const unsigned yp = (unsigned)__shfl_xor((int)y, 32);
          union { unsigned u[4]; bf16x8 v; } pa;
          pa.u[0] = hi ? xp : a;
          pa.u[1] = hi ? yp : bq;
          pa.u[2] = hi ? c : xp;
          pa.u[3] = hi ? d : yp;
          const int cb = (ks * 32 + hi * 16) ^ kswz;
          bf16x8 v0 = *(const bf16x8*)(Vp + l31 * 128 + cb);
          bf16x8 v1 = *(const bf16x8*)(Vp + (32 + l31) * 128 + cb);
          Ot0 = __builtin_amdgcn_mfma_f32_32x32x16_bf16(v0, pa.v, Ot0, 0, 0, 0);
          Ot1 = __builtin_amdgcn_mfma_f32_32x32x16_bf16(v1, pa.v, Ot1, 0, 0, 0);
        }
      }
    }
    __builtin_amdgcn_s_barrier();
    __builtin_amdgcn_sched_barrier(0);
  }

  // ---- epilogue: ctx[q][d] = O^T[d][q] / l ----
  const float inv = 1.0f / l_r;
  ushort* crow = ctx + (size_t)(b * S_ + q_g) * 1024 + h * 64;
#pragma unroll
  for (int g = 0; g < 4; ++g) {
#pragma unroll
    for (int jp = 0; jp < 2; ++jp) {
      const int d0 = 2 * jp + 8 * g + 4 * hi;
      const int r = 4 * g + 2 * jp;
      *(unsigned*)(crow + d0)      = cvtpk(Ot0[r] * inv, Ot0[r + 1] * inv);
      *(unsigned*)(crow + 32 + d0) = cvtpk(Ot1[r] * inv, Ot1[r + 1] * inv);
    }
  }
#undef STAGE_PAIR
}

// ---------------------------------------------------------------- residual + LayerNorm (ao in bf16)
__global__ __launch_bounds__(256) void resid_ln(const float* __restrict__ x,
                                                const ushort* __restrict__ ao,
                                                const float* __restrict__ gamma,
                                                const float* __restrict__ beta,
                                                float* __restrict__ out) {
  const int row = blockIdx.x;
  const int tid = threadIdx.x;
  const size_t base = (size_t)row * E_;

  float4 xv = reinterpret_cast<const float4*>(x + base)[tid];
  ushort4 au = reinterpret_cast<const ushort4*>(ao + base)[tid];
  const float v0 = xv.x + bf2f(au.x), v1 = xv.y + bf2f(au.y);
  const float v2 = xv.z + bf2f(au.z), v3 = xv.w + bf2f(au.w);
  float s  = v0 + v1 + v2 + v3;
  float s2 = v0 * v0 + v1 * v1 + v2 * v2 + v3 * v3;
#pragma unroll
  for (int off = 32; off >= 1; off >>= 1) {
    s  += __shfl_xor(s, off);
    s2 += __shfl_xor(s2, off);
  }
  __shared__ float red[8];
  const int wid = tid >> 6, lane = tid & 63;
  if (lane == 0) { red[wid] = s; red[4 + wid] = s2; }
  __syncthreads();
  s  = red[0] + red[1] + red[2] + red[3];
  s2 = red[4] + red[5] + red[6] + red[7];
  const float mu  = s * (1.f / E_);
  const float var = s2 * (1.f / E_) - mu * mu;
  const float rsd = rsqrtf(var + 1e-5f);

  float4 gv = reinterpret_cast<const float4*>(gamma)[tid];
  float4 bv = reinterpret_cast<const float4*>(beta)[tid];
  float4 ov;
  ov.x = (v0 - mu) * rsd * gv.x + bv.x;
  ov.y = (v1 - mu) * rsd * gv.y + bv.y;
  ov.z = (v2 - mu) * rsd * gv.z + bv.z;
  ov.w = (v3 - mu) * rsd * gv.w + bv.w;
  reinterpret_cast<float4*>(out + base)[tid] = ov;
}

// ---------------------------------------------------------------- launch
extern "C" void kernel_launch(void* const* d_in, const int* in_sizes, int n_in,
                              void* d_out, int out_size, void* d_ws, size_t ws_size,
                              hipStream_t stream) {
  (void)in_sizes; (void)n_in; (void)out_size; (void)ws_size;
  const float* x     = (const float*)d_in[0];
  const float* w_in  = (const float*)d_in[1];
  const float* b_in  = (const float*)d_in[2];
  const float* w_out = (const float*)d_in[3];
  const float* b_out = (const float*)d_in[4];
  const float* gamma = (const float*)d_in[5];
  const float* beta  = (const float*)d_in[6];
  float* out = (float*)d_out;

  char* ws = (char*)d_ws;
  ushort* xb    = (ushort*)(ws);                          // 16 MB
  ushort* winb  = (ushort*)(ws + 16777216);               // 6 MB
  ushort* woutb = (ushort*)(ws + 23068672);               // 2 MB
  ushort* qkb   = (ushort*)(ws + 25165824);               // 32 MB  [8192][2048]
  ushort* vTb   = (ushort*)(ws + 58720256);               // 16 MB  [4096][2048]
  ushort* ctxb  = (ushort*)(ws + 75497472);               // 16 MB
  ushort* aob   = (ushort*)(ws + 92274688);               // 16 MB  bf16 attn-out

  cvt_all<<<dim3(2048), 256, 0, stream>>>(x, w_in, w_out, xb, winb, woutb);

  gemm_bt2<1><<<dim3(1536), 256, 0, stream>>>(xb, winb, b_in, qkb, vTb, E3_, E_);
  attn_causal<<<dim3(512), 512, 0, stream>>>(qkb, vTb, ctxb);
  gemm_bt2<0><<<dim3(512), 256, 0, stream>>>(ctxb, woutb, b_out, aob, nullptr, E_, E_);
  resid_ln<<<dim3(M_), 256, 0, stream>>>(x, aob, gamma, beta, out);
}